// Round 7
// baseline (495.952 us; speedup 1.0000x reference)
//
#include <hip/hip_runtime.h>
#include <math.h>

#define BB 8
#define CC 32
#define TT 9
#define LL 512
#define HH 8
#define DD 4
#define NBT (BB*TT)          // 72
#define RELN (2*LL-1)        // 1023
#define RLN2 1.4426950408889634f

typedef float v2f __attribute__((ext_vector_type(2)));

// ---- mixed bias, reversed + log2e-prescaled: mbr[Ho][x] = log2e * sum_h rpb[h][1022-x] Wl[h][Ho]
// (consumer index: x = j - i + 511  <=>  rel idx i - j + 511 = 1022 - x)
__global__ void mixed_bias_kernel(const float* __restrict__ rpb,
                                  const float* __restrict__ Wl,
                                  float* __restrict__ mbr) {
  int x = blockIdx.x * blockDim.x + threadIdx.x;
  if (x >= RELN) return;
  int idx = 1022 - x;
  float r[HH];
  #pragma unroll
  for (int h = 0; h < HH; ++h) r[h] = rpb[h*RELN + idx];
  #pragma unroll
  for (int Ho = 0; Ho < HH; ++Ho) {
    float acc = 0.f;
    #pragma unroll
    for (int h = 0; h < HH; ++h) acc += r[h] * Wl[h*HH + Ho];
    mbr[Ho*1024 + x] = RLN2 * acc;
  }
}

// ---------------- transpose pl_w (512x512): outT[l][l'] = in[l'][l] ----------------
__global__ __launch_bounds__(256) void transpose512_kernel(const float* __restrict__ in,
                                                           float* __restrict__ outT) {
  __shared__ float tile[32][33];
  int bx = blockIdx.x * 32, by = blockIdx.y * 32;
  int tx = threadIdx.x & 31, ty = threadIdx.x >> 5;   // 32x8
  #pragma unroll
  for (int yy = ty; yy < 32; yy += 8)
    tile[yy][tx] = in[(by + yy)*LL + bx + tx];
  __syncthreads();
  #pragma unroll
  for (int yy = ty; yy < 32; yy += 8)
    outT[(bx + yy)*LL + by + tx] = tile[tx][yy];
}

// ---------------- q/k/v projection + l2norm ----------------
// q: [bt][h][l][d], scaled by 0.5*log2e (1/sqrt(D) and exp2 prescale folded in)
// k,v: [bt][l][h*4+d]   (128 B contiguous per token -> uniform 16 B loads in attn)
__global__ __launch_bounds__(256) void proj_kernel(
    const float* __restrict__ x,
    const float* __restrict__ Wq, const float* __restrict__ bq,
    const float* __restrict__ Wk, const float* __restrict__ bk,
    const float* __restrict__ Wv, const float* __restrict__ bv,
    float* __restrict__ qo, float* __restrict__ ko, float* __restrict__ vo) {
  int g = blockIdx.x * 256 + threadIdx.x;    // 0..36863
  int l  = g & (LL-1);
  int bt = g >> 9;
  int b = bt / TT, t = bt - b*TT;

  float xv[CC];
  #pragma unroll
  for (int c = 0; c < CC; ++c)
    xv[c] = x[((b*CC + c)*TT + t)*LL + l];

  const float* Ws[3] = {Wq, Wk, Wv};
  const float* bs[3] = {bq, bk, bv};
  #pragma unroll
  for (int p = 0; p < 3; ++p) {
    const float* W = Ws[p];
    const float* bi = bs[p];
    const float post = (p == 0) ? 0.5f * RLN2 : 1.0f;
    #pragma unroll
    for (int h = 0; h < HH; ++h) {
      float yv[DD];
      #pragma unroll
      for (int d = 0; d < DD; ++d) {
        int co = h*DD + d;
        float acc = bi[co];
        #pragma unroll
        for (int ci = 0; ci < CC; ++ci) acc += xv[ci] * W[co*CC + ci];
        yv[d] = acc;
      }
      float n = sqrtf(yv[0]*yv[0] + yv[1]*yv[1] + yv[2]*yv[2] + yv[3]*yv[3]);
      float inv = post / fmaxf(n, 1e-12f);
      float4 o4 = make_float4(yv[0]*inv, yv[1]*inv, yv[2]*inv, yv[3]*inv);
      if (p == 0)
        *reinterpret_cast<float4*>(&qo[((size_t)(bt*HH + h))*(LL*DD) + l*DD]) = o4;
      else if (p == 1)
        *reinterpret_cast<float4*>(&ko[((size_t)(bt*LL) + l)*CC + h*DD]) = o4;
      else
        *reinterpret_cast<float4*>(&vo[((size_t)(bt*LL) + l)*CC + h*DD]) = o4;
    }
  }
}

// ---------------- fused attention (v6: lane-owns-row + cross-wave PV reduce) ----------------
// 576 blocks x 256 thr. Block = (bt, row-group of 64 rows). Lane owns row i.
// Wave wv covers j in [wv*128,(wv+1)*128). Pass1: S partials -> LDS reduce.
// Pass2: recompute scores, normalize, mix2+PV -> opart LDS -> cooperative
// cross-wave reduce + coalesced write. K/V reads wave-uniform (broadcast).
__global__ __launch_bounds__(256, 2) void attn_kernel(
    const float* __restrict__ q, const float* __restrict__ k, const float* __restrict__ v,
    const float* __restrict__ Wl, const float* __restrict__ Wc,
    const float* __restrict__ mbr, float* __restrict__ xatt) {
  __shared__ float sS[4][64][9];        // padded: write stride 9 (bank-friendly)
  __shared__ float opart[4][64][33];    // padded: lane stride 33 -> conflict-free

  // XCD swizzle: 576 blocks, 72 per XCD; one bt's 8 groups stay on one XCD
  const int wgid = blockIdx.x;
  const int id   = (wgid & 7) * 72 + (wgid >> 3);
  const int bt   = id >> 3;     // [0,72)
  const int rg   = id & 7;      // [0,8)

  const int tid  = threadIdx.x;
  const int wv   = __builtin_amdgcn_readfirstlane(tid >> 6);   // uniform
  const int lane = tid & 63;
  const int i    = rg*64 + lane;         // this lane's output row

  // q row: 8 heads x float4 (persists both passes)
  float4 qv[HH];
  {
    const float* qrow = q + ((size_t)(bt*HH))*(LL*DD) + i*DD;
    #pragma unroll
    for (int h = 0; h < HH; ++h)
      qv[h] = *reinterpret_cast<const float4*>(&qrow[h*(LL*DD)]);
  }

  const float* kb = k + ((size_t)bt*LL)*CC;
  const float* vb = v + ((size_t)bt*LL)*CC;
  const int j00 = wv*128;

  // ---------------- pass 1: softmax-denominator partials ----------------
  float Sp[HH];
  #pragma unroll
  for (int H = 0; H < HH; ++H) Sp[H] = 0.f;

  for (int jp = 0; jp < 64; ++jp) {
    const int j0 = j00 + 2*jp;
    const int o  = j0 - i + 511;
    v2f lg2[HH];
    #pragma unroll
    for (int H = 0; H < HH; ++H)
      lg2[H] = (v2f){ mbr[H*1024 + o], mbr[H*1024 + o + 1] };

    const float4* k0 = reinterpret_cast<const float4*>(&kb[(size_t)j0*CC]);
    const float4* k1 = reinterpret_cast<const float4*>(&kb[(size_t)(j0+1)*CC]);
    v2f s2[HH];
    #pragma unroll
    for (int h = 0; h < HH; ++h) {
      float4 a = k0[h], c = k1[h];
      s2[h][0] = qv[h].x*a.x + qv[h].y*a.y + qv[h].z*a.z + qv[h].w*a.w;
      s2[h][1] = qv[h].x*c.x + qv[h].y*c.y + qv[h].z*c.z + qv[h].w*c.w;
    }
    #pragma unroll
    for (int h = 0; h < HH; ++h) {
      #pragma unroll
      for (int H = 0; H < HH; ++H) {
        float w = Wl[h*HH + H];
        lg2[H] += s2[h] * (v2f){w, w};
      }
    }
    #pragma unroll
    for (int H = 0; H < HH; ++H)
      Sp[H] += exp2f(lg2[H][0]) + exp2f(lg2[H][1]);
  }

  // ---------------- exchange S partials ----------------
  #pragma unroll
  for (int H = 0; H < HH; ++H) sS[wv][lane][H] = Sp[H];
  __syncthreads();
  float inv[HH];
  #pragma unroll
  for (int H = 0; H < HH; ++H) {
    float s = sS[0][lane][H] + sS[1][lane][H] + sS[2][lane][H] + sS[3][lane][H];
    inv[H] = __builtin_amdgcn_rcpf(s);
  }

  // ---------------- pass 2: recompute scores, normalize, mix2 + PV ----------------
  v2f acc2[16];
  #pragma unroll
  for (int e = 0; e < 16; ++e) acc2[e] = (v2f){0.f, 0.f};

  for (int jp = 0; jp < 64; ++jp) {
    const int j0 = j00 + 2*jp;
    const int o  = j0 - i + 511;
    v2f lg2[HH];
    #pragma unroll
    for (int H = 0; H < HH; ++H)
      lg2[H] = (v2f){ mbr[H*1024 + o], mbr[H*1024 + o + 1] };

    const float4* k0 = reinterpret_cast<const float4*>(&kb[(size_t)j0*CC]);
    const float4* k1 = reinterpret_cast<const float4*>(&kb[(size_t)(j0+1)*CC]);
    v2f s2[HH];
    #pragma unroll
    for (int h = 0; h < HH; ++h) {
      float4 a = k0[h], c = k1[h];
      s2[h][0] = qv[h].x*a.x + qv[h].y*a.y + qv[h].z*a.z + qv[h].w*a.w;
      s2[h][1] = qv[h].x*c.x + qv[h].y*c.y + qv[h].z*c.z + qv[h].w*c.w;
    }
    #pragma unroll
    for (int h = 0; h < HH; ++h) {
      #pragma unroll
      for (int H = 0; H < HH; ++H) {
        float w = Wl[h*HH + H];
        lg2[H] += s2[h] * (v2f){w, w};
      }
    }
    v2f e2[HH];
    #pragma unroll
    for (int H = 0; H < HH; ++H) {
      e2[H] = (v2f){ exp2f(lg2[H][0]), exp2f(lg2[H][1]) } * (v2f){inv[H], inv[H]};
    }

    const float4* v0 = reinterpret_cast<const float4*>(&vb[(size_t)j0*CC]);
    const float4* v1 = reinterpret_cast<const float4*>(&vb[(size_t)(j0+1)*CC]);
    #pragma unroll
    for (int Hp = 0; Hp < HH; ++Hp) {
      v2f a2;
      {
        float w = Wc[Hp];
        a2 = e2[0] * (v2f){w, w};
      }
      #pragma unroll
      for (int H = 1; H < HH; ++H) {
        float w = Wc[H*HH + Hp];
        a2 += e2[H] * (v2f){w, w};
      }
      float4 va = v0[Hp], vc = v1[Hp];
      acc2[Hp*2+0] += (v2f){a2[0], a2[0]} * (v2f){va.x, va.y}
                    + (v2f){a2[1], a2[1]} * (v2f){vc.x, vc.y};
      acc2[Hp*2+1] += (v2f){a2[0], a2[0]} * (v2f){va.z, va.w}
                    + (v2f){a2[1], a2[1]} * (v2f){vc.z, vc.w};
    }
  }

  // ---------------- cross-wave PV reduce + coalesced write ----------------
  #pragma unroll
  for (int e = 0; e < 16; ++e) {
    opart[wv][lane][2*e]     = acc2[e][0];
    opart[wv][lane][2*e + 1] = acc2[e][1];
  }
  __syncthreads();
  #pragma unroll
  for (int kk = 0; kk < 8; ++kk) {
    int g   = kk*256 + tid;      // 0..2047
    int row = g >> 5;            // 0..63
    int e   = g & 31;            // 0..31
    float s = opart[0][row][e] + opart[1][row][e]
            + opart[2][row][e] + opart[3][row][e];
    xatt[((size_t)bt*LL + rg*64 + row)*CC + e] = s;
  }
}

// ---------------- Wm projection; t<8 -> final out, t==8 -> xm8 scratch ----------------
__global__ __launch_bounds__(256) void wm_kernel(
    const float* __restrict__ xatt, const float* __restrict__ Wm, const float* __restrict__ bm,
    float* __restrict__ out, float* __restrict__ xm8) {
  int g = blockIdx.x * 256 + threadIdx.x;
  int l  = g & (LL-1);
  int bt = g >> 9;
  int b = bt / TT, t = bt - b*TT;
  float xv[CC];
  #pragma unroll
  for (int c = 0; c < CC; c += 4) {
    float4 x4 = *reinterpret_cast<const float4*>(&xatt[(size_t)g*CC + c]);
    xv[c] = x4.x; xv[c+1] = x4.y; xv[c+2] = x4.z; xv[c+3] = x4.w;
  }
  #pragma unroll
  for (int co = 0; co < CC; ++co) {
    float acc = bm[co];
    #pragma unroll
    for (int ci = 0; ci < CC; ++ci) acc += xv[ci] * Wm[co*CC + ci];
    if (t < TT-1) out[((b*CC + co)*TT + t)*LL + l] = acc;
    else          xm8[(b*CC + co)*LL + l] = acc;
  }
}

// ---------------- conv over (ci,t) + BN(eval) + ReLU ----------------
__global__ __launch_bounds__(512) void conv_kernel(
    const float* __restrict__ out, const float* __restrict__ pp,
    const float* __restrict__ cw, const float* __restrict__ cb,
    const float* __restrict__ bng, const float* __restrict__ bnb,
    float* __restrict__ yws) {
  int bc = blockIdx.x;            // b*32 + co
  int b = bc >> 5, co = bc & 31;
  int l = threadIdx.x;
  float acc = cb[co];
  #pragma unroll
  for (int ci = 0; ci < CC; ++ci) {
    const float* base = out + ((b*CC + ci)*TT)*LL + l;
    const float* w = cw + (co*CC + ci)*TT;
    #pragma unroll
    for (int t = 0; t < TT-1; ++t) acc += base[t*LL] * w[t];
    acc += pp[ci*LL + l] * w[TT-1];
  }
  float scale = bng[co] * 0.999995000037499687f;   // 1/sqrt(1+1e-5)
  float val = acc * scale + bnb[co];
  yws[bc*LL + l] = fmaxf(val, 0.f);
}

// ---------------- token-linear p = y @ pl_w.T + pl_b; out[t=8] = xm8 - p ----------------
__global__ __launch_bounds__(512) void pl_kernel(
    const float* __restrict__ yws, const float* __restrict__ plwT,
    const float* __restrict__ plb, const float* __restrict__ xm8,
    float* __restrict__ out) {
  __shared__ float sy[2][LL];
  int bc0 = blockIdx.x * 2;
  int tid = threadIdx.x;
  sy[0][tid] = yws[bc0*LL + tid];
  sy[1][tid] = yws[(bc0+1)*LL + tid];
  __syncthreads();
  float acc0 = plb[tid], acc1 = plb[tid];
  #pragma unroll 4
  for (int l = 0; l < LL; ++l) {
    float w = plwT[l*LL + tid];
    acc0 += sy[0][l] * w;
    acc1 += sy[1][l] * w;
  }
  out[(bc0*TT + (TT-1))*LL + tid]       = xm8[bc0*LL + tid] - acc0;
  out[((bc0+1)*TT + (TT-1))*LL + tid]   = xm8[(bc0+1)*LL + tid] - acc1;
}

extern "C" void kernel_launch(void* const* d_in, const int* in_sizes, int n_in,
                              void* d_out, int out_size, void* d_ws, size_t ws_size,
                              hipStream_t stream) {
  const float* x    = (const float*)d_in[0];
  const float* Wq   = (const float*)d_in[1];
  const float* bq   = (const float*)d_in[2];
  const float* Wk   = (const float*)d_in[3];
  const float* bk   = (const float*)d_in[4];
  const float* Wv   = (const float*)d_in[5];
  const float* bv   = (const float*)d_in[6];
  const float* Wm   = (const float*)d_in[7];
  const float* bm   = (const float*)d_in[8];
  const float* Wl   = (const float*)d_in[9];
  const float* Wc   = (const float*)d_in[10];
  const float* rpb  = (const float*)d_in[11];
  const float* pp   = (const float*)d_in[12];
  const float* cw   = (const float*)d_in[13];
  const float* cb   = (const float*)d_in[14];
  const float* bng  = (const float*)d_in[15];
  const float* bnb  = (const float*)d_in[16];
  const float* plw  = (const float*)d_in[17];
  const float* plb  = (const float*)d_in[18];
  float* out = (float*)d_out;

  float* ws = (float*)d_ws;
  const size_t QKV = (size_t)NBT*HH*LL*DD;     // 1179648
  float* q_ws   = ws;                 // QKV
  float* k_ws   = q_ws + QKV;         // QKV (layout [bt][j][32])
  float* v_ws   = k_ws + QKV;         // QKV (layout [bt][j][32])
  float* xatt   = v_ws + QKV;         // NBT*LL*CC = 1179648
  float* xm8    = xatt + QKV;         // BB*CC*LL = 131072
  float* yws    = xm8 + (size_t)BB*CC*LL;      // 131072
  float* plwT   = yws + (size_t)BB*CC*LL;      // 262144
  float* mbias  = plwT + (size_t)LL*LL;        // 8*1024 reversed, log2e-scaled

  mixed_bias_kernel<<<2, 512, 0, stream>>>(rpb, Wl, mbias);
  transpose512_kernel<<<dim3(16,16), 256, 0, stream>>>(plw, plwT);
  proj_kernel<<<(BB*TT*LL)/256, 256, 0, stream>>>(x, Wq, bq, Wk, bk, Wv, bv, q_ws, k_ws, v_ws);
  attn_kernel<<<NBT*8, 256, 0, stream>>>(q_ws, k_ws, v_ws, Wl, Wc, mbias, xatt);
  wm_kernel<<<(BB*TT*LL)/256, 256, 0, stream>>>(xatt, Wm, bm, out, xm8);
  conv_kernel<<<BB*CC, LL, 0, stream>>>(out, pp, cw, cb, bng, bnb, yws);
  pl_kernel<<<(BB*CC)/2, LL, 0, stream>>>(yws, plwT, plb, xm8, out);
}